// Round 2
// baseline (3477.321 us; speedup 1.0000x reference)
//
#include <hip/hip_runtime.h>
#include <hip/hip_bf16.h>

#define CC 64

// ---------------- node projection kernel: h = relu(x@W_in^T + b); a_src/a_dst/xv = h@W^T ----
__global__ __launch_bounds__(256) void node_proj_kernel(
    const float* __restrict__ x,
    const float* __restrict__ W_in, const float* __restrict__ b_in,
    const float* __restrict__ W_src, const float* __restrict__ W_dst, const float* __restrict__ W_lin,
    float* __restrict__ a_src, float* __restrict__ a_dst, float* __restrict__ xv, int N)
{
    __shared__ float xt[64][65];
    __shared__ float ht[64][65];
    __shared__ float wt[64][65];
    const int t = threadIdx.x, lane = t & 63, quad = t >> 6;
    const int n0 = blockIdx.x * 64;
    #pragma unroll 4
    for (int i = 0; i < 16; ++i) {
        int r = i*4 + quad, n = n0 + r;
        xt[r][lane] = (n < N) ? x[(size_t)n*CC + lane] : 0.f;
        wt[lane][r] = W_in[(size_t)r*CC + lane];   // wt[k][o] = W_in[o][k]
    }
    __syncthreads();
    const float bi = b_in[lane];
    #pragma unroll 4
    for (int i = 0; i < 16; ++i) {
        int r = i*4 + quad;
        float acc = bi;
        #pragma unroll
        for (int k = 0; k < 64; ++k) acc += xt[r][k] * wt[k][lane];
        ht[r][lane] = fmaxf(acc, 0.f);
    }
    __syncthreads();
    const float* Ws[3] = {W_src, W_dst, W_lin};
    float* Os[3] = {a_src, a_dst, xv};
    #pragma unroll
    for (int m = 0; m < 3; ++m) {
        #pragma unroll 4
        for (int i = 0; i < 16; ++i) {
            int r = i*4 + quad;
            wt[lane][r] = Ws[m][(size_t)r*CC + lane];
        }
        __syncthreads();
        #pragma unroll 4
        for (int i = 0; i < 16; ++i) {
            int r = i*4 + quad, n = n0 + r;
            float acc = 0.f;
            #pragma unroll
            for (int k = 0; k < 64; ++k) acc += ht[r][k] * wt[k][lane];
            if (n < N) Os[m][(size_t)n*CC + lane] = acc;
        }
        __syncthreads();
    }
}

// monotone float->uint transform (order-preserving incl. negatives)
__device__ __forceinline__ unsigned fmono(float f) {
    unsigned u = __float_as_uint(f);
    return u ^ ((unsigned)((int)u >> 31) | 0x80000000u);
}

// dot of the 64-wide LDS-broadcast vector with a per-lane register column
__device__ __forceinline__ float dot64(const float* vsh, const float* w, float bias) {
    float a0 = 0.f, a1 = 0.f, a2 = 0.f, a3 = 0.f;
    const float4* v4 = (const float4*)vsh;
    #pragma unroll
    for (int i = 0; i < 16; ++i) {
        float4 v = v4[i];
        a0 += v.x * w[4*i+0];
        a1 += v.y * w[4*i+1];
        a2 += v.z * w[4*i+2];
        a3 += v.w * w[4*i+3];
    }
    return (a0 + a1) + (a2 + a3) + bias;
}

// ---------------- edge kernels: PASS 0 -> amax; PASS 1 -> esum + max(e*(xv+delta)) ----------
template<int PASS>
__global__ __launch_bounds__(256, 2) void edge_kernel(
    const int* __restrict__ ei, const float* __restrict__ pos,
    const float* __restrict__ a_src, const float* __restrict__ a_dst,
    const float* __restrict__ xv,
    const float* __restrict__ pW1, const float* __restrict__ pb1,
    const float* __restrict__ pW2, const float* __restrict__ pb2,
    const float* __restrict__ aW1, const float* __restrict__ ab1,
    const float* __restrict__ aW2, const float* __restrict__ ab2,
    float* __restrict__ amax, float* __restrict__ esum,
    unsigned* __restrict__ outb,
    int N, int E)
{
    const int lane = threadIdx.x & 63;
    const int wid  = threadIdx.x >> 6;
    __shared__ __align__(16) float vsh_[4][64];
    float* vsh = vsh_[wid];

    // per-lane weight columns in registers
    float wp1[3], wp2[64], wa1[64], wa2[64];
    #pragma unroll
    for (int d = 0; d < 3; ++d) wp1[d] = pW1[d*64 + lane];
    #pragma unroll
    for (int k = 0; k < 64; ++k) wp2[k] = pW2[k*64 + lane];
    #pragma unroll
    for (int k = 0; k < 64; ++k) wa1[k] = aW1[k*64 + lane];
    #pragma unroll
    for (int k = 0; k < 64; ++k) wa2[k] = aW2[k*64 + lane];
    const float bp1 = pb1[lane], bp2 = pb2[lane], ba1 = ab1[lane], ba2 = ab2[lane];

    const long total = (long)E + N;
    const long gw = (long)blockIdx.x * 4 + wid;
    const long nw = (long)gridDim.x * 4;
    for (long e = gw; e < total; e += nw) {
        int s, d;
        float pd0, pd1, pd2;
        if (e < E) {
            s = ei[e]; d = ei[(size_t)E + e];
            s = min(max(s, 0), N-1); d = min(max(d, 0), N-1);
            pd0 = pos[(size_t)d*3+0] - pos[(size_t)s*3+0];
            pd1 = pos[(size_t)d*3+1] - pos[(size_t)s*3+1];
            pd2 = pos[(size_t)d*3+2] - pos[(size_t)s*3+2];
        } else {
            s = d = (int)(e - E);
            pd0 = pd1 = pd2 = 0.f;
        }
        // pos_nn layer 1 (3 -> 64)
        float p1 = fmaxf(pd0*wp1[0] + pd1*wp1[1] + pd2*wp1[2] + bp1, 0.f);
        vsh[lane] = p1;
        __builtin_amdgcn_wave_barrier();
        // pos_nn layer 2 (64 -> 64)
        float delta = fmaxf(dot64(vsh, wp2, bp2), 0.f);
        __builtin_amdgcn_wave_barrier();
        // attn input
        float ad = a_dst[(size_t)d*CC + lane] - a_src[(size_t)s*CC + lane] + delta;
        vsh[lane] = ad;
        __builtin_amdgcn_wave_barrier();
        float h1 = fmaxf(dot64(vsh, wa1, ba1), 0.f);
        __builtin_amdgcn_wave_barrier();
        vsh[lane] = h1;
        __builtin_amdgcn_wave_barrier();
        float a = fmaxf(dot64(vsh, wa2, ba2), 0.f);
        __builtin_amdgcn_wave_barrier();

        if (PASS == 0) {
            // a >= 0, so raw float bits are uint-monotone; amax initialized to 0.0f
            atomicMax((unsigned*)&amax[(size_t)d*CC + lane], __float_as_uint(a));
        } else {
            float mx = amax[(size_t)d*CC + lane];
            float ee = __expf(a - mx);
            atomicAdd(&esum[(size_t)d*CC + lane], ee);
            float m = ee * (xv[(size_t)s*CC + lane] + delta);
            atomicMax(&outb[(size_t)d*CC + lane], fmono(m));
        }
    }
}

// ---------------- output kernel: out = relu((decode(outb)/esum) @ W_out^T + b_out) ----------
__global__ __launch_bounds__(256) void out_kernel(
    const unsigned* outb_in,            // aliases out -- no restrict
    const float* __restrict__ esum,
    const float* __restrict__ W_out, const float* __restrict__ b_out,
    float* out, int N)
{
    __shared__ float vt[64][65];
    __shared__ float wt[64][65];
    const int t = threadIdx.x, lane = t & 63, quad = t >> 6;
    const int n0 = blockIdx.x * 64;
    #pragma unroll 4
    for (int i = 0; i < 16; ++i) {
        int r = i*4 + quad, n = n0 + r;
        wt[lane][r] = W_out[(size_t)r*CC + lane];
        float v = 0.f;
        if (n < N) {
            unsigned u = outb_in[(size_t)n*CC + lane];
            u = (u >> 31) ? (u ^ 0x80000000u) : ~u;   // inverse of fmono
            v = __uint_as_float(u) / esum[(size_t)n*CC + lane];
        }
        vt[r][lane] = v;
    }
    __syncthreads();
    const float bo = b_out[lane];
    #pragma unroll 4
    for (int i = 0; i < 16; ++i) {
        int r = i*4 + quad, n = n0 + r;
        if (n >= N) continue;
        float acc = bo;
        #pragma unroll
        for (int k = 0; k < 64; ++k) acc += vt[r][k] * wt[k][lane];
        out[(size_t)n*CC + lane] = fmaxf(acc, 0.f);
    }
}

extern "C" void kernel_launch(void* const* d_in, const int* in_sizes, int n_in,
                              void* d_out, int out_size, void* d_ws, size_t ws_size,
                              hipStream_t stream)
{
    const float* x     = (const float*)d_in[0];
    const float* pos   = (const float*)d_in[1];
    const int*   ei    = (const int*)d_in[2];
    const float* W_in  = (const float*)d_in[3];
    const float* b_in  = (const float*)d_in[4];
    const float* W_out = (const float*)d_in[5];
    const float* b_out = (const float*)d_in[6];
    const float* W_lin = (const float*)d_in[7];
    const float* W_src = (const float*)d_in[8];
    const float* W_dst = (const float*)d_in[9];
    const float* pW1   = (const float*)d_in[10];
    const float* pb1   = (const float*)d_in[11];
    const float* pW2   = (const float*)d_in[12];
    const float* pb2   = (const float*)d_in[13];
    const float* aW1   = (const float*)d_in[14];
    const float* ab1   = (const float*)d_in[15];
    const float* aW2   = (const float*)d_in[16];
    const float* ab2   = (const float*)d_in[17];

    const int N = in_sizes[0] / CC;
    const int E = in_sizes[2] / 2;
    const size_t nc = (size_t)N * CC;

    float* ws     = (float*)d_ws;
    float* a_src  = ws;
    float* a_dst  = ws + nc;
    float* xvv    = ws + 2*nc;
    float* amax   = ws + 3*nc;
    float* esum   = ws + 4*nc;
    unsigned* outb = (unsigned*)d_out;

    hipMemsetAsync(amax, 0, nc*sizeof(float), stream);
    hipMemsetAsync(esum, 0, nc*sizeof(float), stream);
    hipMemsetAsync(outb, 0, nc*sizeof(float), stream);

    const int nblk = (N + 63) / 64;
    node_proj_kernel<<<nblk, 256, 0, stream>>>(x, W_in, b_in, W_src, W_dst, W_lin,
                                               a_src, a_dst, xvv, N);
    edge_kernel<0><<<1024, 256, 0, stream>>>(ei, pos, a_src, a_dst, xvv,
                                             pW1, pb1, pW2, pb2, aW1, ab1, aW2, ab2,
                                             amax, esum, outb, N, E);
    edge_kernel<1><<<1024, 256, 0, stream>>>(ei, pos, a_src, a_dst, xvv,
                                             pW1, pb1, pW2, pb2, aW1, ab1, aW2, ab2,
                                             amax, esum, outb, N, E);
    out_kernel<<<nblk, 256, 0, stream>>>(outb, esum, W_out, b_out, (float*)d_out, N);
}

// Round 7
// 2459.492 us; speedup vs baseline: 1.4138x; 1.4138x over previous
//
#include <hip/hip_runtime.h>
#include <hip/hip_bf16.h>

#define CC 64

// ---------------- node projection kernel: h = relu(x@W_in^T + b); a_src/a_dst/xv = h@W^T ----
__global__ __launch_bounds__(256) void node_proj_kernel(
    const float* __restrict__ x,
    const float* __restrict__ W_in, const float* __restrict__ b_in,
    const float* __restrict__ W_src, const float* __restrict__ W_dst, const float* __restrict__ W_lin,
    float* __restrict__ a_src, float* __restrict__ a_dst, float* __restrict__ xv, int N)
{
    __shared__ float xt[64][65];
    __shared__ float ht[64][65];
    __shared__ float wt[64][65];
    const int t = threadIdx.x, lane = t & 63, quad = t >> 6;
    const int n0 = blockIdx.x * 64;
    #pragma unroll 4
    for (int i = 0; i < 16; ++i) {
        int r = i*4 + quad, n = n0 + r;
        xt[r][lane] = (n < N) ? x[(size_t)n*CC + lane] : 0.f;
        wt[lane][r] = W_in[(size_t)r*CC + lane];   // wt[k][o] = W_in[o][k]
    }
    __syncthreads();
    const float bi = b_in[lane];
    #pragma unroll 4
    for (int i = 0; i < 16; ++i) {
        int r = i*4 + quad;
        float acc = bi;
        #pragma unroll
        for (int k = 0; k < 64; ++k) acc += xt[r][k] * wt[k][lane];
        ht[r][lane] = fmaxf(acc, 0.f);
    }
    __syncthreads();
    const float* Ws[3] = {W_src, W_dst, W_lin};
    float* Os[3] = {a_src, a_dst, xv};
    #pragma unroll
    for (int m = 0; m < 3; ++m) {
        #pragma unroll 4
        for (int i = 0; i < 16; ++i) {
            int r = i*4 + quad;
            wt[lane][r] = Ws[m][(size_t)r*CC + lane];
        }
        __syncthreads();
        #pragma unroll 4
        for (int i = 0; i < 16; ++i) {
            int r = i*4 + quad, n = n0 + r;
            float acc = 0.f;
            #pragma unroll
            for (int k = 0; k < 64; ++k) acc += ht[r][k] * wt[k][lane];
            if (n < N) Os[m][(size_t)n*CC + lane] = acc;
        }
        __syncthreads();
    }
}

// monotone float->uint transform (order-preserving incl. negatives)
__device__ __forceinline__ unsigned fmono(float f) {
    unsigned u = __float_as_uint(f);
    return u ^ ((unsigned)((int)u >> 31) | 0x80000000u);
}

// dot of the 64-wide LDS-broadcast vector with a per-lane register column
__device__ __forceinline__ float dot64(const float* vsh, const float* w, float bias) {
    float a0 = 0.f, a1 = 0.f, a2 = 0.f, a3 = 0.f;
    const float4* v4 = (const float4*)vsh;
    #pragma unroll
    for (int i = 0; i < 16; ++i) {
        float4 v = v4[i];
        a0 += v.x * w[4*i+0];
        a1 += v.y * w[4*i+1];
        a2 += v.z * w[4*i+2];
        a3 += v.w * w[4*i+3];
    }
    return (a0 + a1) + (a2 + a3) + bias;
}

// ---------------- single fused edge pass ----------------------------------------------------
// Uses softmax scale-invariance: out = max_e(exp(a)*(xv+delta)) / sum_e exp(a).
// a = relu(attn MLP) >= 0 and statistically bounded (~6 max here), so exp(a) is safe in fp32.
__global__ __launch_bounds__(256, 3) void edge_fused_kernel(
    const int* __restrict__ ei, const float* __restrict__ pos,
    const float* __restrict__ a_src, const float* __restrict__ a_dst,
    const float* __restrict__ xv,
    const float* __restrict__ pW1, const float* __restrict__ pb1,
    const float* __restrict__ pW2, const float* __restrict__ pb2,
    const float* __restrict__ aW1, const float* __restrict__ ab1,
    const float* __restrict__ aW2, const float* __restrict__ ab2,
    float* __restrict__ esum, unsigned* __restrict__ outb,
    int N, int E)
{
    const int lane = threadIdx.x & 63;
    const int wid  = threadIdx.x >> 6;
    __shared__ float wl[64][65];                 // aW2 staged
    __shared__ __align__(16) float vsh_[4][64];
    float* vsh = vsh_[wid];

    for (int i = threadIdx.x; i < 64*64; i += 256)
        wl[i >> 6][i & 63] = aW2[i];

    // per-lane weight columns in registers (pos_nn + attn L1 only: 131 floats)
    float wp1v[3], wp2v[64], wa1v[64];
    #pragma unroll
    for (int d0 = 0; d0 < 3; ++d0) wp1v[d0] = pW1[d0*64 + lane];
    #pragma unroll
    for (int k = 0; k < 64; ++k) wp2v[k] = pW2[k*64 + lane];
    #pragma unroll
    for (int k = 0; k < 64; ++k) wa1v[k] = aW1[k*64 + lane];
    const float bp1 = pb1[lane], bp2 = pb2[lane], ba1 = ab1[lane], ba2 = ab2[lane];
    __syncthreads();

    const long total = (long)E + N;
    const long nw = (long)gridDim.x * 4;
    long e = (long)blockIdx.x * 4 + wid;
    if (e >= total) return;

    // prefetched head of the chain: indices + pos diff
    int cs, cd; float cq0, cq1, cq2;
    if (e < E) {
        cs = ei[e]; cd = ei[(size_t)E + e];
        cs = min(max(cs, 0), N-1); cd = min(max(cd, 0), N-1);
        cq0 = pos[(size_t)cd*3+0] - pos[(size_t)cs*3+0];
        cq1 = pos[(size_t)cd*3+1] - pos[(size_t)cs*3+1];
        cq2 = pos[(size_t)cd*3+2] - pos[(size_t)cs*3+2];
    } else { cs = cd = (int)(e - E); cq0 = cq1 = cq2 = 0.f; }

    while (true) {
        const long en = e + nw;
        const bool hn = en < total;
        int ns = 0, nd = 0; float nq0 = 0.f, nq1 = 0.f, nq2 = 0.f;
        if (hn) {
            if (en < E) {
                ns = ei[en]; nd = ei[(size_t)E + en];
                ns = min(max(ns, 0), N-1); nd = min(max(nd, 0), N-1);
                nq0 = pos[(size_t)nd*3+0] - pos[(size_t)ns*3+0];
                nq1 = pos[(size_t)nd*3+1] - pos[(size_t)ns*3+1];
                nq2 = pos[(size_t)nd*3+2] - pos[(size_t)ns*3+2];
            } else { ns = nd = (int)(en - E); }
        }

        // issue row gathers now; values first needed ~250cy later (after delta)
        const float cgd = a_dst[(size_t)cd*CC + lane];
        const float cgs = a_src[(size_t)cs*CC + lane];
        const float cgx = xv   [(size_t)cs*CC + lane];

        // pos_nn layer 1 (3 -> 64)
        float p1 = fmaxf(cq0*wp1v[0] + cq1*wp1v[1] + cq2*wp1v[2] + bp1, 0.f);
        vsh[lane] = p1;
        __builtin_amdgcn_wave_barrier();
        // pos_nn layer 2 (64 -> 64)
        float delta = fmaxf(dot64(vsh, wp2v, bp2), 0.f);
        __builtin_amdgcn_wave_barrier();
        // attn input
        float ad = cgd - cgs + delta;
        vsh[lane] = ad;
        __builtin_amdgcn_wave_barrier();
        float h1 = fmaxf(dot64(vsh, wa1v, ba1), 0.f);
        __builtin_amdgcn_wave_barrier();
        vsh[lane] = h1;
        __builtin_amdgcn_wave_barrier();
        // attn layer 2 from LDS weights: a[j] = sum_k h1[k] * wl[k][j]
        float acc = ba2;
        const float4* v4 = (const float4*)vsh;
        #pragma unroll
        for (int kk = 0; kk < 16; ++kk) {
            float4 h = v4[kk];
            acc += h.x * wl[4*kk+0][lane];
            acc += h.y * wl[4*kk+1][lane];
            acc += h.z * wl[4*kk+2][lane];
            acc += h.w * wl[4*kk+3][lane];
        }
        __builtin_amdgcn_wave_barrier();
        float a = fmaxf(acc, 0.f);

        float ee = __expf(a);
        atomicAdd(&esum[(size_t)cd*CC + lane], ee);
        float m = ee * (cgx + delta);
        atomicMax(&outb[(size_t)cd*CC + lane], fmono(m));

        if (!hn) break;
        cs = ns; cd = nd; cq0 = nq0; cq1 = nq1; cq2 = nq2;
        e = en;
    }
}

// ---------------- output kernel: out = relu((decode(outb)/esum) @ W_out^T + b_out) ----------
__global__ __launch_bounds__(256) void out_kernel(
    const unsigned* outb_in,            // aliases out -- no restrict
    const float* __restrict__ esum,
    const float* __restrict__ W_out, const float* __restrict__ b_out,
    float* out, int N)
{
    __shared__ float vt[64][65];
    __shared__ float wt[64][65];
    const int t = threadIdx.x, lane = t & 63, quad = t >> 6;
    const int n0 = blockIdx.x * 64;
    #pragma unroll 4
    for (int i = 0; i < 16; ++i) {
        int r = i*4 + quad, n = n0 + r;
        wt[lane][r] = W_out[(size_t)r*CC + lane];
        float v = 0.f;
        if (n < N) {
            unsigned u = outb_in[(size_t)n*CC + lane];
            u = (u >> 31) ? (u ^ 0x80000000u) : ~u;   // inverse of fmono
            v = __uint_as_float(u) / esum[(size_t)n*CC + lane];
        }
        vt[r][lane] = v;
    }
    __syncthreads();
    const float bo = b_out[lane];
    #pragma unroll 4
    for (int i = 0; i < 16; ++i) {
        int r = i*4 + quad, n = n0 + r;
        if (n >= N) continue;
        float acc = bo;
        #pragma unroll
        for (int k = 0; k < 64; ++k) acc += vt[r][k] * wt[k][lane];
        out[(size_t)n*CC + lane] = fmaxf(acc, 0.f);
    }
}

extern "C" void kernel_launch(void* const* d_in, const int* in_sizes, int n_in,
                              void* d_out, int out_size, void* d_ws, size_t ws_size,
                              hipStream_t stream)
{
    const float* x     = (const float*)d_in[0];
    const float* pos   = (const float*)d_in[1];
    const int*   ei    = (const int*)d_in[2];
    const float* W_in  = (const float*)d_in[3];
    const float* b_in  = (const float*)d_in[4];
    const float* W_out = (const float*)d_in[5];
    const float* b_out = (const float*)d_in[6];
    const float* W_lin = (const float*)d_in[7];
    const float* W_src = (const float*)d_in[8];
    const float* W_dst = (const float*)d_in[9];
    const float* pW1   = (const float*)d_in[10];
    const float* pb1   = (const float*)d_in[11];
    const float* pW2   = (const float*)d_in[12];
    const float* pb2   = (const float*)d_in[13];
    const float* aW1   = (const float*)d_in[14];
    const float* ab1   = (const float*)d_in[15];
    const float* aW2   = (const float*)d_in[16];
    const float* ab2   = (const float*)d_in[17];

    const int N = in_sizes[0] / CC;
    const int E = in_sizes[2] / 2;
    const size_t nc = (size_t)N * CC;

    float* ws     = (float*)d_ws;
    float* a_src  = ws;
    float* a_dst  = ws + nc;
    float* xvv    = ws + 2*nc;
    float* esum   = ws + 3*nc;
    unsigned* outb = (unsigned*)d_out;

    hipMemsetAsync(esum, 0, nc*sizeof(float), stream);
    hipMemsetAsync(outb, 0, nc*sizeof(float), stream);

    const int nblk = (N + 63) / 64;
    node_proj_kernel<<<nblk, 256, 0, stream>>>(x, W_in, b_in, W_src, W_dst, W_lin,
                                               a_src, a_dst, xvv, N);
    edge_fused_kernel<<<1536, 256, 0, stream>>>(ei, pos, a_src, a_dst, xvv,
                                                pW1, pb1, pW2, pb2, aW1, ab1, aW2, ab2,
                                                esum, outb, N, E);
    out_kernel<<<nblk, 256, 0, stream>>>(outb, esum, W_out, b_out, (float*)d_out, N);
}

// Round 8
// 1053.566 us; speedup vs baseline: 3.3005x; 2.3344x over previous
//
#include <hip/hip_runtime.h>
#include <hip/hip_bf16.h>

#define CC 64

typedef __attribute__((ext_vector_type(8))) short s16x8;
typedef __attribute__((ext_vector_type(4))) float f32x4;

__device__ __forceinline__ unsigned short f2b(float f) {   // f32 -> bf16 bits, RNE
    unsigned u = __float_as_uint(f);
    u += 0x7FFF + ((u >> 16) & 1);
    return (unsigned short)(u >> 16);
}
__device__ __forceinline__ unsigned fmono(float f) {       // order-preserving f32->u32
    unsigned u = __float_as_uint(f);
    return u ^ ((unsigned)((int)u >> 31) | 0x80000000u);
}

// ---- node kernel: h=relu(x@W_in^T+b); AS=(h@W_src^T)@aW1; AD=(h@W_dst^T)@aW1; xv=h@W_lin^T
__global__ __launch_bounds__(256) void node_proj_kernel(
    const float* __restrict__ x,
    const float* __restrict__ W_in, const float* __restrict__ b_in,
    const float* __restrict__ W_src, const float* __restrict__ W_dst,
    const float* __restrict__ W_lin, const float* __restrict__ aW1,
    float* __restrict__ AS, float* __restrict__ AD, float* __restrict__ xvv, int N)
{
    __shared__ float xt[64][65];   // doubles as tt after h is built
    __shared__ float ht[64][65];
    __shared__ float wt[64][65];
    const int t = threadIdx.x, lane = t & 63, quad = t >> 6;
    const int n0 = blockIdx.x * 64;
    #pragma unroll 4
    for (int i = 0; i < 16; ++i) {
        int r = i*4 + quad, n = n0 + r;
        xt[r][lane] = (n < N) ? x[(size_t)n*CC + lane] : 0.f;
        wt[lane][r] = W_in[(size_t)r*CC + lane];
    }
    __syncthreads();
    const float bi = b_in[lane];
    #pragma unroll 4
    for (int i = 0; i < 16; ++i) {
        int r = i*4 + quad;
        float acc = bi;
        #pragma unroll
        for (int k = 0; k < 64; ++k) acc += xt[r][k] * wt[k][lane];
        ht[r][lane] = fmaxf(acc, 0.f);
    }
    __syncthreads();

    const float* Wm[2] = {W_src, W_dst};
    float* Om[2] = {AS, AD};
    #pragma unroll
    for (int m = 0; m < 2; ++m) {
        #pragma unroll 4
        for (int i = 0; i < 16; ++i) { int r = i*4+quad; wt[lane][r] = Wm[m][(size_t)r*CC + lane]; }
        __syncthreads();
        #pragma unroll 4
        for (int i = 0; i < 16; ++i) {             // tt = h @ Wm^T   (linear, no relu)
            int r = i*4+quad; float acc = 0.f;
            #pragma unroll
            for (int k = 0; k < 64; ++k) acc += ht[r][k] * wt[k][lane];
            xt[r][lane] = acc;
        }
        __syncthreads();
        #pragma unroll 4
        for (int i = 0; i < 16; ++i) { int r = i*4+quad; wt[r][lane] = aW1[(size_t)r*CC + lane]; }
        __syncthreads();
        #pragma unroll 4
        for (int i = 0; i < 16; ++i) {             // out = tt @ aW1
            int r = i*4+quad, n = n0 + r; float acc = 0.f;
            #pragma unroll
            for (int k = 0; k < 64; ++k) acc += xt[r][k] * wt[k][lane];
            if (n < N) Om[m][(size_t)n*CC + lane] = acc;
        }
        __syncthreads();
    }
    #pragma unroll 4
    for (int i = 0; i < 16; ++i) { int r = i*4+quad; wt[lane][r] = W_lin[(size_t)r*CC + lane]; }
    __syncthreads();
    #pragma unroll 4
    for (int i = 0; i < 16; ++i) {
        int r = i*4+quad, n = n0 + r; float acc = 0.f;
        #pragma unroll
        for (int k = 0; k < 64; ++k) acc += ht[r][k] * wt[k][lane];
        if (n < N) xvv[(size_t)n*CC + lane] = acc;
    }
}

// ---- edge kernel: 16 edges per wave per iteration, 3 bf16 MFMA matvec layers --------------
__global__ __launch_bounds__(256, 2) void edge_mfma_kernel(
    const int* __restrict__ ei, const float* __restrict__ pos,
    const float* __restrict__ AD, const float* __restrict__ AS, const float* __restrict__ xv,
    const float* __restrict__ pW1, const float* __restrict__ pb1,
    const float* __restrict__ pW2, const float* __restrict__ pb2,
    const float* __restrict__ aW1, const float* __restrict__ ab1,
    const float* __restrict__ aW2, const float* __restrict__ ab2,
    float* __restrict__ esum, unsigned* __restrict__ outb,
    int N, int E)
{
    const int tid = threadIdx.x;
    const int lane = tid & 63;
    const int wid  = tid >> 6;
    const int lm = lane & 15;          // A-row / D-col index
    const int lg = lane >> 4;          // k-group / D-row group

    __shared__ __align__(16) unsigned short swt[3][64 * 72];   // W^T staged as bf16 [out][k]
    __shared__ __align__(16) unsigned short tb[4][16 * 72];    // per-wave transpose buffer

    {   // one-time staging: swt[w][o][k] = bf16(W[k][o])
        const float* Wsrc[3] = {pW2, aW1, aW2};
        #pragma unroll
        for (int w = 0; w < 3; ++w)
            for (int idx = tid; idx < 4096; idx += 256) {
                int k = idx >> 6, o = idx & 63;
                swt[w][o*72 + k] = f2b(Wsrc[w][idx]);
            }
    }
    __syncthreads();

    // resident B fragments: Bf[w][t][h] covers cols [16t,16t+16), k in [32h,32h+32)
    s16x8 Bf[3][4][2];
    #pragma unroll
    for (int w = 0; w < 3; ++w)
        #pragma unroll
        for (int tt = 0; tt < 4; ++tt)
            #pragma unroll
            for (int h = 0; h < 2; ++h)
                Bf[w][tt][h] = *(const s16x8*)&swt[w][(lm + 16*tt)*72 + 32*h + lg*8];

    // pW1/pb1 packed bf16 per-lane constants (k = lg*8 + (j&7) + 32*(j>>3))
    unsigned pwA[16], pwB[16];
    #pragma unroll
    for (int j = 0; j < 16; ++j) {
        int k = lg*8 + (j & 7) + 32*(j >> 3);
        pwA[j] = (unsigned)f2b(pW1[k])       | ((unsigned)f2b(pW1[64+k]) << 16);
        pwB[j] = (unsigned)f2b(pW1[128+k])   | ((unsigned)f2b(pb1[k])    << 16);
    }
    float pb2v[4], ab1v[4], ab2v[4];
    #pragma unroll
    for (int tt = 0; tt < 4; ++tt) {
        pb2v[tt] = pb2[lm + 16*tt];
        ab1v[tt] = ab1[lm + 16*tt];
        ab2v[tt] = ab2[lm + 16*tt];
    }

    unsigned short* tbw = tb[wid];
    const long total = (long)E + N;
    const long ntiles = (total + 15) >> 4;
    const long nwv = (long)gridDim.x * 4;

    for (long tile = (long)blockIdx.x * 4 + wid; tile < ntiles; tile += nwv) {
        const long base = tile << 4;

        // ---- p-path indices (edge = base + lm) -> pos diff ----
        long ep = base + lm;
        int sp, dp;
        if (ep < E) {
            sp = ei[ep]; dp = ei[(size_t)E + ep];
            sp = min(max(sp, 0), N-1); dp = min(max(dp, 0), N-1);
        } else {
            long v = ep - E; if (v > N-1) v = N-1;
            sp = dp = (int)v;
        }
        float q0 = pos[(size_t)dp*3+0] - pos[(size_t)sp*3+0];
        float q1 = pos[(size_t)dp*3+1] - pos[(size_t)sp*3+1];
        float q2 = pos[(size_t)dp*3+2] - pos[(size_t)sp*3+2];

        // ---- gather-path indices (edges base + lg*4 + r) ----
        int sg[4], dg[4]; int actm = 0;
        #pragma unroll
        for (int r = 0; r < 4; ++r) {
            long eg = base + lg*4 + r;
            if (eg < total) actm |= (1 << r);
            if (eg < E) {
                int s = ei[eg], d = ei[(size_t)E + eg];
                sg[r] = min(max(s,0),N-1); dg[r] = min(max(d,0),N-1);
            } else {
                long v = eg - E; if (v > N-1) v = N-1; if (v < 0) v = 0;
                sg[r] = dg[r] = (int)v;
            }
        }

        // ---- p1 = relu(pdiff@pW1 + pb1) built directly in A-frag layout ----
        s16x8 Alo, Ahi;
        #pragma unroll
        for (int j = 0; j < 16; ++j) {
            float w0 = __uint_as_float(pwA[j] << 16);
            float w1 = __uint_as_float(pwA[j] & 0xFFFF0000u);
            float w2 = __uint_as_float(pwB[j] << 16);
            float bb = __uint_as_float(pwB[j] & 0xFFFF0000u);
            float v = fmaxf(fmaf(q0, w0, fmaf(q1, w1, fmaf(q2, w2, bb))), 0.f);
            short b = (short)f2b(v);
            if (j < 8) Alo[j] = b; else Ahi[j-8] = b;
        }

        // ---- layer 1: delta = relu(p1 @ pW2 + pb2)  (D-layout) ----
        f32x4 dlt[4];
        #pragma unroll
        for (int tt = 0; tt < 4; ++tt) {
            f32x4 z = {0.f, 0.f, 0.f, 0.f};
            z = __builtin_amdgcn_mfma_f32_16x16x32_bf16(Alo, Bf[0][tt][0], z, 0, 0, 0);
            z = __builtin_amdgcn_mfma_f32_16x16x32_bf16(Ahi, Bf[0][tt][1], z, 0, 0, 0);
            #pragma unroll
            for (int r = 0; r < 4; ++r) dlt[tt][r] = fmaxf(z[r] + pb2v[tt], 0.f);
        }

        // ---- transpose 1: delta -> A frags ----
        #pragma unroll
        for (int tt = 0; tt < 4; ++tt)
            #pragma unroll
            for (int r = 0; r < 4; ++r)
                tbw[(lg*4+r)*72 + lm + 16*tt] = f2b(dlt[tt][r]);
        __builtin_amdgcn_wave_barrier();
        s16x8 Dlo = *(const s16x8*)&tbw[lm*72 + lg*8];
        s16x8 Dhi = *(const s16x8*)&tbw[lm*72 + 32 + lg*8];
        __builtin_amdgcn_wave_barrier();

        // ---- AD/AS gathers (consumed after layer-2 MFMA) ----
        float gad[4][4], gas[4][4];
        #pragma unroll
        for (int r = 0; r < 4; ++r)
            #pragma unroll
            for (int tt = 0; tt < 4; ++tt) {
                gad[r][tt] = AD[(size_t)dg[r]*CC + lm + 16*tt];
                gas[r][tt] = AS[(size_t)sg[r]*CC + lm + 16*tt];
            }

        // ---- layer 2: h1 = relu(AD[d]-AS[s] + delta@aW1 + ab1) -> transpose 2 ----
        #pragma unroll
        for (int tt = 0; tt < 4; ++tt) {
            f32x4 z = {0.f, 0.f, 0.f, 0.f};
            z = __builtin_amdgcn_mfma_f32_16x16x32_bf16(Dlo, Bf[1][tt][0], z, 0, 0, 0);
            z = __builtin_amdgcn_mfma_f32_16x16x32_bf16(Dhi, Bf[1][tt][1], z, 0, 0, 0);
            #pragma unroll
            for (int r = 0; r < 4; ++r) {
                float v = fmaxf(z[r] + gad[r][tt] - gas[r][tt] + ab1v[tt], 0.f);
                tbw[(lg*4+r)*72 + lm + 16*tt] = f2b(v);
            }
        }
        __builtin_amdgcn_wave_barrier();
        s16x8 Hlo = *(const s16x8*)&tbw[lm*72 + lg*8];
        s16x8 Hhi = *(const s16x8*)&tbw[lm*72 + 32 + lg*8];
        __builtin_amdgcn_wave_barrier();

        // ---- xv gathers ----
        float gxv[4][4];
        #pragma unroll
        for (int r = 0; r < 4; ++r)
            #pragma unroll
            for (int tt = 0; tt < 4; ++tt)
                gxv[r][tt] = xv[(size_t)sg[r]*CC + lm + 16*tt];

        // ---- layer 3: a = relu(h1@aW2 + ab2); ee = exp(a); atomics ----
        #pragma unroll
        for (int tt = 0; tt < 4; ++tt) {
            f32x4 z = {0.f, 0.f, 0.f, 0.f};
            z = __builtin_amdgcn_mfma_f32_16x16x32_bf16(Hlo, Bf[2][tt][0], z, 0, 0, 0);
            z = __builtin_amdgcn_mfma_f32_16x16x32_bf16(Hhi, Bf[2][tt][1], z, 0, 0, 0);
            #pragma unroll
            for (int r = 0; r < 4; ++r) {
                float a  = fmaxf(z[r] + ab2v[tt], 0.f);
                float ee = __expf(a);
                if (actm & (1 << r)) {
                    size_t off = (size_t)dg[r]*CC + lm + 16*tt;
                    atomicAdd(&esum[off], ee);
                    float m = ee * (gxv[r][tt] + dlt[tt][r]);
                    atomicMax(&outb[off], fmono(m));
                }
            }
        }
    }
}

// ---- output kernel: out = relu((decode(outb)/esum) @ W_out^T + b_out) --------------------
__global__ __launch_bounds__(256) void out_kernel(
    const unsigned* outb_in,            // aliases out -- no restrict
    const float* __restrict__ esum,
    const float* __restrict__ W_out, const float* __restrict__ b_out,
    float* out, int N)
{
    __shared__ float vt[64][65];
    __shared__ float wt[64][65];
    const int t = threadIdx.x, lane = t & 63, quad = t >> 6;
    const int n0 = blockIdx.x * 64;
    #pragma unroll 4
    for (int i = 0; i < 16; ++i) {
        int r = i*4 + quad, n = n0 + r;
        wt[lane][r] = W_out[(size_t)r*CC + lane];
        float v = 0.f;
        if (n < N) {
            unsigned u = outb_in[(size_t)n*CC + lane];
            u = (u >> 31) ? (u ^ 0x80000000u) : ~u;   // inverse of fmono
            v = __uint_as_float(u) / esum[(size_t)n*CC + lane];
        }
        vt[r][lane] = v;
    }
    __syncthreads();
    const float bo = b_out[lane];
    #pragma unroll 4
    for (int i = 0; i < 16; ++i) {
        int r = i*4 + quad, n = n0 + r;
        if (n >= N) continue;
        float acc = bo;
        #pragma unroll
        for (int k = 0; k < 64; ++k) acc += vt[r][k] * wt[k][lane];
        out[(size_t)n*CC + lane] = fmaxf(acc, 0.f);
    }
}

extern "C" void kernel_launch(void* const* d_in, const int* in_sizes, int n_in,
                              void* d_out, int out_size, void* d_ws, size_t ws_size,
                              hipStream_t stream)
{
    const float* x     = (const float*)d_in[0];
    const float* pos   = (const float*)d_in[1];
    const int*   ei    = (const int*)d_in[2];
    const float* W_in  = (const float*)d_in[3];
    const float* b_in  = (const float*)d_in[4];
    const float* W_out = (const float*)d_in[5];
    const float* b_out = (const float*)d_in[6];
    const float* W_lin = (const float*)d_in[7];
    const float* W_src = (const float*)d_in[8];
    const float* W_dst = (const float*)d_in[9];
    const float* pW1   = (const float*)d_in[10];
    const float* pb1   = (const float*)d_in[11];
    const float* pW2   = (const float*)d_in[12];
    const float* pb2   = (const float*)d_in[13];
    const float* aW1   = (const float*)d_in[14];
    const float* ab1   = (const float*)d_in[15];
    const float* aW2   = (const float*)d_in[16];
    const float* ab2   = (const float*)d_in[17];

    const int N = in_sizes[0] / CC;
    const int E = in_sizes[2] / 2;
    const size_t nc = (size_t)N * CC;

    float* ws   = (float*)d_ws;
    float* AS   = ws;
    float* AD   = ws + nc;
    float* xvv  = ws + 2*nc;
    float* esum = ws + 3*nc;
    unsigned* outb = (unsigned*)d_out;

    hipMemsetAsync(esum, 0, nc*sizeof(float), stream);
    hipMemsetAsync(outb, 0, nc*sizeof(float), stream);

    const int nblk = (N + 63) / 64;
    node_proj_kernel<<<nblk, 256, 0, stream>>>(x, W_in, b_in, W_src, W_dst, W_lin, aW1,
                                               AS, AD, xvv, N);
    edge_mfma_kernel<<<2048, 256, 0, stream>>>(ei, pos, AD, AS, xvv,
                                               pW1, pb1, pW2, pb2, aW1, ab1, aW2, ab2,
                                               esum, outb, N, E);
    out_kernel<<<nblk, 256, 0, stream>>>(outb, esum, W_out, b_out, (float*)d_out, N);
}

// Round 9
// 1024.277 us; speedup vs baseline: 3.3949x; 1.0286x over previous
//
#include <hip/hip_runtime.h>
#include <hip/hip_bf16.h>

#define CC 64

typedef __attribute__((ext_vector_type(8))) short s16x8;
typedef __attribute__((ext_vector_type(4))) float f32x4;

__device__ __forceinline__ unsigned short f2b(float f) {   // f32 -> bf16 bits, RNE
    unsigned u = __float_as_uint(f);
    u += 0x7FFF + ((u >> 16) & 1);
    return (unsigned short)(u >> 16);
}
__device__ __forceinline__ unsigned fmono(float f) {       // order-preserving f32->u32
    unsigned u = __float_as_uint(f);
    return u ^ ((unsigned)((int)u >> 31) | 0x80000000u);
}

// ---- node kernel: h=relu(x@W_in^T+b); AS=(h@W_src^T)@aW1; AD=(h@W_dst^T)@aW1; xv=h@W_lin^T
// Weights per-lane in registers (lane = output channel); activations via LDS broadcast.
__global__ __launch_bounds__(256, 2) void node_proj_kernel(
    const float* __restrict__ x,
    const float* __restrict__ W_in, const float* __restrict__ b_in,
    const float* __restrict__ W_src, const float* __restrict__ W_dst,
    const float* __restrict__ W_lin, const float* __restrict__ aW1,
    float* __restrict__ AS, float* __restrict__ AD, float* __restrict__ xvv, int N)
{
    __shared__ float xt[64][68];   // input rows (x, then tmp)
    __shared__ float ht[64][68];   // h rows
    const int t = threadIdx.x, lane = t & 63, quad = t >> 6;
    const int n0 = blockIdx.x * 64;
    float wreg[64];

    #pragma unroll 4
    for (int i = 0; i < 16; ++i) {
        int r = i*4 + quad, n = n0 + r;
        xt[r][lane] = (n < N) ? x[(size_t)n*CC + lane] : 0.f;
    }
    #pragma unroll
    for (int k4 = 0; k4 < 16; ++k4)
        *(float4*)&wreg[k4*4] = *(const float4*)&W_in[(size_t)lane*CC + k4*4];
    const float bi = b_in[lane];
    __syncthreads();

    #pragma unroll 2
    for (int i = 0; i < 16; ++i) {
        int r = i*4 + quad;
        float acc = bi;
        #pragma unroll
        for (int k4 = 0; k4 < 16; ++k4) {
            float4 xx = *(const float4*)&xt[r][k4*4];
            acc += xx.x*wreg[k4*4+0] + xx.y*wreg[k4*4+1]
                 + xx.z*wreg[k4*4+2] + xx.w*wreg[k4*4+3];
        }
        ht[r][lane] = fmaxf(acc, 0.f);
    }
    __syncthreads();

    const float* Wm[2] = {W_src, W_dst};
    float* Om[2] = {AS, AD};
    #pragma unroll
    for (int m = 0; m < 2; ++m) {
        #pragma unroll
        for (int k4 = 0; k4 < 16; ++k4)
            *(float4*)&wreg[k4*4] = *(const float4*)&Wm[m][(size_t)lane*CC + k4*4];
        #pragma unroll 2
        for (int i = 0; i < 16; ++i) {              // tmp = h @ Wm^T (linear)
            int r = i*4 + quad;
            float acc = 0.f;
            #pragma unroll
            for (int k4 = 0; k4 < 16; ++k4) {
                float4 xx = *(const float4*)&ht[r][k4*4];
                acc += xx.x*wreg[k4*4+0] + xx.y*wreg[k4*4+1]
                     + xx.z*wreg[k4*4+2] + xx.w*wreg[k4*4+3];
            }
            xt[r][lane] = acc;
        }
        __syncthreads();
        #pragma unroll
        for (int k = 0; k < 64; ++k) wreg[k] = aW1[(size_t)k*CC + lane];
        #pragma unroll 2
        for (int i = 0; i < 16; ++i) {              // Om = tmp @ aW1
            int r = i*4 + quad, n = n0 + r;
            float acc = 0.f;
            #pragma unroll
            for (int k4 = 0; k4 < 16; ++k4) {
                float4 xx = *(const float4*)&xt[r][k4*4];
                acc += xx.x*wreg[k4*4+0] + xx.y*wreg[k4*4+1]
                     + xx.z*wreg[k4*4+2] + xx.w*wreg[k4*4+3];
            }
            if (n < N) Om[m][(size_t)n*CC + lane] = acc;
        }
        __syncthreads();
    }

    #pragma unroll
    for (int k4 = 0; k4 < 16; ++k4)
        *(float4*)&wreg[k4*4] = *(const float4*)&W_lin[(size_t)lane*CC + k4*4];
    #pragma unroll 2
    for (int i = 0; i < 16; ++i) {
        int r = i*4 + quad, n = n0 + r;
        float acc = 0.f;
        #pragma unroll
        for (int k4 = 0; k4 < 16; ++k4) {
            float4 xx = *(const float4*)&ht[r][k4*4];
            acc += xx.x*wreg[k4*4+0] + xx.y*wreg[k4*4+1]
                 + xx.z*wreg[k4*4+2] + xx.w*wreg[k4*4+3];
        }
        if (n < N) xvv[(size_t)n*CC + lane] = acc;
    }
}

// ---- edge kernel: 16 edges/wave/iter, 3 bf16 MFMA layers; all weights in LDS -------------
__global__ __launch_bounds__(256, 3) void edge_mfma_kernel(
    const int* __restrict__ ei, const float* __restrict__ pos,
    const float* __restrict__ AD, const float* __restrict__ AS, const float* __restrict__ xv,
    const float* __restrict__ pW1, const float* __restrict__ pb1,
    const float* __restrict__ pW2, const float* __restrict__ pb2,
    const float* __restrict__ aW1, const float* __restrict__ ab1,
    const float* __restrict__ aW2, const float* __restrict__ ab2,
    float* __restrict__ esum, unsigned* __restrict__ outb,
    int N, int E)
{
    const int tid = threadIdx.x;
    const int lane = tid & 63;
    const int wid  = tid >> 6;
    const int lm = lane & 15;          // A-row / D-col index
    const int lg = lane >> 4;          // k-group / D-row group

    __shared__ __align__(16) unsigned short swt[3][64 * 72];   // W^T bf16 [out][k]
    __shared__ __align__(16) unsigned short tb[4][16 * 72];    // per-wave transpose buffer
    __shared__ unsigned spw[2][64];                            // packed pW1/pb1

    {
        const float* Wsrc[3] = {pW2, aW1, aW2};
        #pragma unroll
        for (int w = 0; w < 3; ++w)
            for (int idx = tid; idx < 4096; idx += 256) {
                int k = idx >> 6, o = idx & 63;
                swt[w][o*72 + k] = f2b(Wsrc[w][idx]);
            }
        if (tid < 64) {
            spw[0][tid] = (unsigned)f2b(pW1[tid])     | ((unsigned)f2b(pW1[64+tid]) << 16);
            spw[1][tid] = (unsigned)f2b(pW1[128+tid]) | ((unsigned)f2b(pb1[tid])    << 16);
        }
    }
    __syncthreads();

    float pb2v[4], ab1v[4], ab2v[4];
    #pragma unroll
    for (int tt = 0; tt < 4; ++tt) {
        pb2v[tt] = pb2[lm + 16*tt];
        ab1v[tt] = ab1[lm + 16*tt];
        ab2v[tt] = ab2[lm + 16*tt];
    }

    unsigned short* tbw = tb[wid];
    const long total = (long)E + N;
    const long ntiles = (total + 15) >> 4;
    const long nwv = (long)gridDim.x * 4;

    for (long tile = (long)blockIdx.x * 4 + wid; tile < ntiles; tile += nwv) {
        const long base = tile << 4;

        // ---- p-path indices (edge = base + lm) -> pos diff ----
        long ep = base + lm;
        int sp, dp;
        if (ep < E) {
            sp = ei[ep]; dp = ei[(size_t)E + ep];
            sp = min(max(sp, 0), N-1); dp = min(max(dp, 0), N-1);
        } else {
            long v = ep - E; if (v > N-1) v = N-1;
            sp = dp = (int)v;
        }
        float q0 = pos[(size_t)dp*3+0] - pos[(size_t)sp*3+0];
        float q1 = pos[(size_t)dp*3+1] - pos[(size_t)sp*3+1];
        float q2 = pos[(size_t)dp*3+2] - pos[(size_t)sp*3+2];

        // ---- gather-path indices (edges base + lg*4 + r) ----
        int sg[4], dg[4]; int actm = 0;
        #pragma unroll
        for (int r = 0; r < 4; ++r) {
            long eg = base + lg*4 + r;
            if (eg < total) actm |= (1 << r);
            if (eg < E) {
                int s = ei[eg], d = ei[(size_t)E + eg];
                sg[r] = min(max(s,0),N-1); dg[r] = min(max(d,0),N-1);
            } else {
                long v = eg - E; if (v > N-1) v = N-1; if (v < 0) v = 0;
                sg[r] = dg[r] = (int)v;
            }
        }

        // ---- p1 = relu(pdiff@pW1 + pb1) built directly in A-frag layout ----
        s16x8 Alo, Ahi;
        #pragma unroll
        for (int j = 0; j < 16; ++j) {
            int k = lg*8 + (j & 7) + 32*(j >> 3);
            unsigned wa = ((volatile unsigned*)spw[0])[k];
            unsigned wb = ((volatile unsigned*)spw[1])[k];
            float w0 = __uint_as_float(wa << 16);
            float w1 = __uint_as_float(wa & 0xFFFF0000u);
            float w2 = __uint_as_float(wb << 16);
            float bb = __uint_as_float(wb & 0xFFFF0000u);
            float v = fmaxf(fmaf(q0, w0, fmaf(q1, w1, fmaf(q2, w2, bb))), 0.f);
            short b = (short)f2b(v);
            if (j < 8) Alo[j] = b; else Ahi[j-8] = b;
        }

        // ---- layer 1: delta = relu(p1 @ pW2 + pb2)  (D-layout) ----
        f32x4 dlt[4];
        #pragma unroll
        for (int tt = 0; tt < 4; ++tt) {
            s16x8 b0 = *(const s16x8*)&swt[0][(lm + 16*tt)*72 + lg*8];
            s16x8 b1 = *(const s16x8*)&swt[0][(lm + 16*tt)*72 + 32 + lg*8];
            f32x4 z = {0.f, 0.f, 0.f, 0.f};
            z = __builtin_amdgcn_mfma_f32_16x16x32_bf16(Alo, b0, z, 0, 0, 0);
            z = __builtin_amdgcn_mfma_f32_16x16x32_bf16(Ahi, b1, z, 0, 0, 0);
            #pragma unroll
            for (int r = 0; r < 4; ++r) dlt[tt][r] = fmaxf(z[r] + pb2v[tt], 0.f);
        }

        // ---- transpose 1: delta -> A frags ----
        #pragma unroll
        for (int tt = 0; tt < 4; ++tt)
            #pragma unroll
            for (int r = 0; r < 4; ++r)
                tbw[(lg*4+r)*72 + lm + 16*tt] = f2b(dlt[tt][r]);
        __builtin_amdgcn_wave_barrier();
        s16x8 Dlo = *(const s16x8*)&tbw[lm*72 + lg*8];
        s16x8 Dhi = *(const s16x8*)&tbw[lm*72 + 32 + lg*8];
        __builtin_amdgcn_wave_barrier();

        // ---- fused AD-AS gathers ----
        float gd[4][4];
        #pragma unroll
        for (int r = 0; r < 4; ++r)
            #pragma unroll
            for (int tt = 0; tt < 4; ++tt)
                gd[r][tt] = AD[(size_t)dg[r]*CC + lm + 16*tt]
                          - AS[(size_t)sg[r]*CC + lm + 16*tt];

        // ---- layer 2: h1 = relu(gd + delta@aW1 + ab1) -> transpose 2 ----
        #pragma unroll
        for (int tt = 0; tt < 4; ++tt) {
            s16x8 b0 = *(const s16x8*)&swt[1][(lm + 16*tt)*72 + lg*8];
            s16x8 b1 = *(const s16x8*)&swt[1][(lm + 16*tt)*72 + 32 + lg*8];
            f32x4 z = {0.f, 0.f, 0.f, 0.f};
            z = __builtin_amdgcn_mfma_f32_16x16x32_bf16(Dlo, b0, z, 0, 0, 0);
            z = __builtin_amdgcn_mfma_f32_16x16x32_bf16(Dhi, b1, z, 0, 0, 0);
            #pragma unroll
            for (int r = 0; r < 4; ++r) {
                float v = fmaxf(z[r] + gd[r][tt] + ab1v[tt], 0.f);
                tbw[(lg*4+r)*72 + lm + 16*tt] = f2b(v);
            }
        }
        __builtin_amdgcn_wave_barrier();
        s16x8 Hlo = *(const s16x8*)&tbw[lm*72 + lg*8];
        s16x8 Hhi = *(const s16x8*)&tbw[lm*72 + 32 + lg*8];
        __builtin_amdgcn_wave_barrier();

        // ---- xv gathers ----
        float gxv[4][4];
        #pragma unroll
        for (int r = 0; r < 4; ++r)
            #pragma unroll
            for (int tt = 0; tt < 4; ++tt)
                gxv[r][tt] = xv[(size_t)sg[r]*CC + lm + 16*tt];

        // ---- layer 3: a = relu(h1@aW2 + ab2); ee = exp(a); atomics ----
        #pragma unroll
        for (int tt = 0; tt < 4; ++tt) {
            s16x8 b0 = *(const s16x8*)&swt[2][(lm + 16*tt)*72 + lg*8];
            s16x8 b1 = *(const s16x8*)&swt[2][(lm + 16*tt)*72 + 32 + lg*8];
            f32x4 z = {0.f, 0.f, 0.f, 0.f};
            z = __builtin_amdgcn_mfma_f32_16x16x32_bf16(Hlo, b0, z, 0, 0, 0);
            z = __builtin_amdgcn_mfma_f32_16x16x32_bf16(Hhi, b1, z, 0, 0, 0);
            #pragma unroll
            for (int r = 0; r < 4; ++r) {
                float a  = fmaxf(z[r] + ab2v[tt], 0.f);
                float ee = __expf(a);
                if (actm & (1 << r)) {
                    size_t off = (size_t)dg[r]*CC + lm + 16*tt;
                    atomicAdd(&esum[off], ee);
                    float m = ee * (gxv[r][tt] + dlt[tt][r]);
                    atomicMax(&outb[off], fmono(m));
                }
            }
        }
    }
}

// ---- output kernel: out = relu((decode(outb)/esum) @ W_out^T + b_out) --------------------
__global__ __launch_bounds__(256, 2) void out_kernel(
    const unsigned* outb_in,            // aliases out -- no restrict
    const float* __restrict__ esum,
    const float* __restrict__ W_out, const float* __restrict__ b_out,
    float* out, int N)
{
    __shared__ float vt[64][68];
    const int t = threadIdx.x, lane = t & 63, quad = t >> 6;
    const int n0 = blockIdx.x * 64;
    float wreg[64];
    #pragma unroll
    for (int k4 = 0; k4 < 16; ++k4)
        *(float4*)&wreg[k4*4] = *(const float4*)&W_out[(size_t)lane*CC + k4*4];
    #pragma unroll 4
    for (int i = 0; i < 16; ++i) {
        int r = i*4 + quad, n = n0 + r;
        float v = 0.f;
        if (n < N) {
            unsigned u = outb_in[(size_t)n*CC + lane];
            u = (u >> 31) ? (u ^ 0x80000000u) : ~u;   // inverse of fmono
            v = __uint_as_float(u) / esum[(size_t)n*CC + lane];
        }
        vt[r][lane] = v;
    }
    __syncthreads();
    const float bo = b_out[lane];
    #pragma unroll 2
    for (int i = 0; i < 16; ++i) {
        int r = i*4 + quad, n = n0 + r;
        if (n >= N) continue;
        float acc = bo;
        #pragma unroll
        for (int k4 = 0; k4 < 16; ++k4) {
            float4 xx = *(const float4*)&vt[r][k4*4];
            acc += xx.x*wreg[k4*4+0] + xx.y*wreg[k4*4+1]
                 + xx.z*wreg[k4*4+2] + xx.w*wreg[k4*4+3];
        }
        out[(size_t)n*CC + lane] = fmaxf(acc, 0.f);
    }
}

extern "C" void kernel_launch(void* const* d_in, const int* in_sizes, int n_in,
                              void* d_out, int out_size, void* d_ws, size_t ws_size,
                              hipStream_t stream)
{
    const float* x     = (const float*)d_in[0];
    const float* pos   = (const float*)d_in[1];
    const int*   ei    = (const int*)d_in[2];
    const float* W_in  = (const float*)d_in[3];
    const float* b_in  = (const float*)d_in[4];
    const float* W_out = (const float*)d_in[5];
    const float* b_out = (const float*)d_in[6];
    const float* W_lin = (const float*)d_in[7];
    const float* W_src = (const float*)d_in[8];
    const float* W_dst = (const float*)d_in[9];
    const float* pW1   = (const float*)d_in[10];
    const float* pb1   = (const float*)d_in[11];
    const float* pW2   = (const float*)d_in[12];
    const float* pb2   = (const float*)d_in[13];
    const float* aW1   = (const float*)d_in[14];
    const float* ab1   = (const float*)d_in[15];
    const float* aW2   = (const float*)d_in[16];
    const float* ab2   = (const float*)d_in[17];

    const int N = in_sizes[0] / CC;
    const int E = in_sizes[2] / 2;
    const size_t nc = (size_t)N * CC;

    float* ws   = (float*)d_ws;
    float* AS   = ws;
    float* AD   = ws + nc;
    float* xvv  = ws + 2*nc;
    float* esum = ws + 3*nc;
    unsigned* outb = (unsigned*)d_out;

    hipMemsetAsync(esum, 0, nc*sizeof(float), stream);
    hipMemsetAsync(outb, 0, nc*sizeof(float), stream);

    const int nblk = (N + 63) / 64;
    node_proj_kernel<<<nblk, 256, 0, stream>>>(x, W_in, b_in, W_src, W_dst, W_lin, aW1,
                                               AS, AD, xvv, N);
    edge_mfma_kernel<<<2048, 256, 0, stream>>>(ei, pos, AD, AS, xvv,
                                               pW1, pb1, pW2, pb2, aW1, ab1, aW2, ab2,
                                               esum, outb, N, E);
    out_kernel<<<nblk, 256, 0, stream>>>(outb, esum, W_out, b_out, (float*)d_out, N);
}